// Round 1
// baseline (1024.038 us; speedup 1.0000x reference)
//
#include <hip/hip_runtime.h>
#include <hip/hip_bf16.h>
#include <cstdint>

// Problem: out_re = x_re@Re^T - x_im@Im^T ; out_im = x_re@Im^T + x_im@Re^T
// Folded into one GEMM: A = [x_re | x_im]  (M x 1024, bf16)
//                       Bt[o][k] per complex structure (1024 x 1024, bf16)
//                       C columns [0,512) -> out_re, [512,1024) -> out_im
#define NROWS 100000
#define MPAD  100096        // 782 * 128
#define KDIM  1024
#define MTILES 782

typedef __attribute__((ext_vector_type(8))) __bf16 bf16x8;
typedef __attribute__((ext_vector_type(4))) float  f32x4;

__device__ __forceinline__ uint16_t f2bf(float f) {
    union { float f; uint32_t u; } v; v.f = f;
    uint32_t u = v.u;
    u += 0x7FFFu + ((u >> 16) & 1u);   // RNE
    return (uint16_t)(u >> 16);
}

__device__ __forceinline__ void async16(const uint16_t* g, uint16_t* l) {
    // global -> LDS direct copy, 16B per lane (global_load_lds_dwordx4)
    __builtin_amdgcn_global_load_lds(
        (const __attribute__((address_space(1))) uint32_t*)g,
        (__attribute__((address_space(3))) uint32_t*)l,
        16, 0, 0);
}

// ---------------- pack A: [x_re | x_im] -> bf16, zero pad rows ----------------
__global__ __launch_bounds__(256) void pack_a_kernel(
        const float* __restrict__ xre, const float* __restrict__ xim,
        uint16_t* __restrict__ A) {
    int c = blockIdx.x * 256 + threadIdx.x;   // 16B chunk (8 bf16); 128 chunks/row
    int n = c >> 7;
    int j = c & 127;                          // wave-uniform re/im split (j<64 vs >=64)
    uint32_t p0 = 0, p1 = 0, p2 = 0, p3 = 0;
    if (n < NROWS) {
        const float* src = (j < 64) ? (xre + (size_t)n * 512 + (size_t)j * 8)
                                    : (xim + (size_t)n * 512 + (size_t)(j - 64) * 8);
        float4 a = ((const float4*)src)[0];
        float4 b = ((const float4*)src)[1];
        p0 = (uint32_t)f2bf(a.x) | ((uint32_t)f2bf(a.y) << 16);
        p1 = (uint32_t)f2bf(a.z) | ((uint32_t)f2bf(a.w) << 16);
        p2 = (uint32_t)f2bf(b.x) | ((uint32_t)f2bf(b.y) << 16);
        p3 = (uint32_t)f2bf(b.z) | ((uint32_t)f2bf(b.w) << 16);
    }
    uint4 v; v.x = p0; v.y = p1; v.z = p2; v.w = p3;
    *(uint4*)(A + (size_t)c * 8) = v;
}

// ------------- pack Bt: [[Re, -Im],[Im, Re]] row-major (o_c, k) bf16 -------------
__global__ __launch_bounds__(256) void pack_b_kernel(
        const float* __restrict__ Re, const float* __restrict__ Im,
        uint16_t* __restrict__ Bt) {
    int c  = blockIdx.x * 256 + threadIdx.x;  // 8 bf16 per chunk; 128 chunks/row
    int oc = c >> 7;
    int j  = c & 127;
    const float* src;
    float sgn = 1.0f;
    if (oc < 512) {
        if (j < 64) { src = Re + (size_t)oc * 512 + (size_t)j * 8; }
        else        { src = Im + (size_t)oc * 512 + (size_t)(j - 64) * 8; sgn = -1.0f; }
    } else {
        int o = oc - 512;
        if (j < 64) { src = Im + (size_t)o * 512 + (size_t)j * 8; }
        else        { src = Re + (size_t)o * 512 + (size_t)(j - 64) * 8; }
    }
    float4 a = ((const float4*)src)[0];
    float4 b = ((const float4*)src)[1];
    uint32_t p0 = (uint32_t)f2bf(sgn * a.x) | ((uint32_t)f2bf(sgn * a.y) << 16);
    uint32_t p1 = (uint32_t)f2bf(sgn * a.z) | ((uint32_t)f2bf(sgn * a.w) << 16);
    uint32_t p2 = (uint32_t)f2bf(sgn * b.x) | ((uint32_t)f2bf(sgn * b.y) << 16);
    uint32_t p3 = (uint32_t)f2bf(sgn * b.z) | ((uint32_t)f2bf(sgn * b.w) << 16);
    uint4 v; v.x = p0; v.y = p1; v.z = p2; v.w = p3;
    *(uint4*)(Bt + (size_t)c * 8) = v;
}

// ---------------- GEMM: 128x128 tile, BK=32, 4 waves of 64x64 ----------------
// LDS granule swizzle: 16B granule (row,kk) stored at index row*4 + (kk ^ (row&3))
// -> spreads ds_read_b128 banks evenly; staging order stays contiguous per wave
// as global_load_lds requires (wave-uniform base + lane*16).
__global__ __launch_bounds__(256) void gemm_kernel(
        const uint16_t* __restrict__ A, const uint16_t* __restrict__ Bt,
        float* __restrict__ C) {
    __shared__ uint16_t As[128 * 32];   // 8 KB
    __shared__ uint16_t Bs[128 * 32];   // 8 KB

    const int t    = threadIdx.x;
    const int wave = t >> 6;
    const int lane = t & 63;
    const int q    = lane >> 4;         // k-quad: k = q*8 + j
    const int r16  = lane & 15;
    const int wm   = wave >> 1;         // 2x2 waves -> 64x64 each
    const int wn   = wave & 1;

    const int colTile = blockIdx.x;     // 0..7  (fastest -> A row-tile L3 reuse)
    const int rowTile = blockIdx.y;     // 0..781

    const size_t aRow0 = (size_t)rowTile * 128;
    const size_t bRow0 = (size_t)colTile * 128;

    // staging: 2 granules per array per thread; granule g holds global chunk
    // (row = g>>2, kk = (g&3) ^ (row&3))
    const int g0 = t, g1 = t + 256;
    const int row0 = g0 >> 2, kk0 = (g0 & 3) ^ (row0 & 3);
    const int row1 = g1 >> 2, kk1 = (g1 & 3) ^ (row1 & 3);

    const uint16_t* gA0 = A  + (aRow0 + row0) * KDIM + kk0 * 8;
    const uint16_t* gA1 = A  + (aRow0 + row1) * KDIM + kk1 * 8;
    const uint16_t* gB0 = Bt + (bRow0 + row0) * KDIM + kk0 * 8;
    const uint16_t* gB1 = Bt + (bRow0 + row1) * KDIM + kk1 * 8;
    uint16_t* lA0 = As + g0 * 8;
    uint16_t* lA1 = As + g1 * 8;
    uint16_t* lB0 = Bs + g0 * 8;
    uint16_t* lB1 = Bs + g1 * 8;

    // LDS read granules for MFMA fragments (A: m=r16, k=q*8+j; B symmetric)
    int gra[4], grb[4];
#pragma unroll
    for (int mi = 0; mi < 4; ++mi) {
        int row = wm * 64 + mi * 16 + r16;
        gra[mi] = row * 4 + (q ^ (row & 3));
    }
#pragma unroll
    for (int ni = 0; ni < 4; ++ni) {
        int row = wn * 64 + ni * 16 + r16;
        grb[ni] = row * 4 + (q ^ (row & 3));
    }

    f32x4 acc[4][4] = {};

    for (int kt = 0; kt < 32; ++kt) {
        const size_t koff = (size_t)kt * 32;
        async16(gA0 + koff, lA0);
        async16(gA1 + koff, lA1);
        async16(gB0 + koff, lB0);
        async16(gB1 + koff, lB1);
        __syncthreads();               // compiler drains vmcnt before barrier

        bf16x8 af[4], bfr[4];
#pragma unroll
        for (int mi = 0; mi < 4; ++mi)
            af[mi] = *(const bf16x8*)(As + gra[mi] * 8);
#pragma unroll
        for (int ni = 0; ni < 4; ++ni)
            bfr[ni] = *(const bf16x8*)(Bs + grb[ni] * 8);

#pragma unroll
        for (int mi = 0; mi < 4; ++mi)
#pragma unroll
            for (int ni = 0; ni < 4; ++ni)
                acc[mi][ni] = __builtin_amdgcn_mfma_f32_16x16x32_bf16(
                    af[mi], bfr[ni], acc[mi][ni], 0, 0, 0);

        __syncthreads();
    }

    // epilogue: C/D layout col = lane&15, row = q*4 + reg  (m89/m91 verified)
    const size_t outHalf = (colTile < 4) ? 0 : (size_t)NROWS * 512;
    const int cbase = (colTile & 3) * 128 + wn * 64;
#pragma unroll
    for (int mi = 0; mi < 4; ++mi) {
        int rbase = rowTile * 128 + wm * 64 + mi * 16 + q * 4;
#pragma unroll
        for (int ni = 0; ni < 4; ++ni) {
            int col = cbase + ni * 16 + r16;
#pragma unroll
            for (int r = 0; r < 4; ++r) {
                int row = rbase + r;
                if (row < NROWS)
                    C[outHalf + (size_t)row * 512 + col] = acc[mi][ni][r];
            }
        }
    }
}

// ---------------- fp32 fallback (only if ws too small for bf16 A) ----------------
__global__ void fallback_kernel(const float* __restrict__ xre,
                                const float* __restrict__ xim,
                                const float* __restrict__ Re,
                                const float* __restrict__ Im,
                                float* __restrict__ out) {
    __shared__ float sre[512], sim[512];
    int n = blockIdx.x;
    for (int i = threadIdx.x; i < 512; i += 256) {
        sre[i] = xre[(size_t)n * 512 + i];
        sim[i] = xim[(size_t)n * 512 + i];
    }
    __syncthreads();
    for (int o = threadIdx.x; o < 512; o += 256) {
        float are = 0.f, aim = 0.f;
        for (int k = 0; k < 512; ++k) {
            float wr = Re[(size_t)o * 512 + k], wi = Im[(size_t)o * 512 + k];
            float xr = sre[k], xi = sim[k];
            are += xr * wr - xi * wi;
            aim += xr * wi + xi * wr;
        }
        out[(size_t)n * 512 + o] = are;
        out[(size_t)NROWS * 512 + (size_t)n * 512 + o] = aim;
    }
}

extern "C" void kernel_launch(void* const* d_in, const int* in_sizes, int n_in,
                              void* d_out, int out_size, void* d_ws, size_t ws_size,
                              hipStream_t stream) {
    const float* xre = (const float*)d_in[0];
    const float* xim = (const float*)d_in[1];
    const float* Re  = (const float*)d_in[2];
    const float* Im  = (const float*)d_in[3];
    float* out = (float*)d_out;

    const size_t aBytes = (size_t)MPAD * KDIM * 2;            // 204,996,608
    const size_t bBytes = (size_t)1024 * KDIM * 2;            // 2 MiB
    if (ws_size >= aBytes + bBytes) {
        uint16_t* A  = (uint16_t*)d_ws;
        uint16_t* Bt = (uint16_t*)((char*)d_ws + aBytes);
        pack_a_kernel<<<(MPAD * 128) / 256, 256, 0, stream>>>(xre, xim, A);
        pack_b_kernel<<<(1024 * 128) / 256, 256, 0, stream>>>(Re, Im, Bt);
        dim3 grid(8, MTILES);
        gemm_kernel<<<grid, 256, 0, stream>>>(A, Bt, out);
    } else {
        fallback_kernel<<<NROWS, 256, 0, stream>>>(xre, xim, Re, Im, out);
    }
}